// Round 1
// 230.348 us; speedup vs baseline: 1.0500x; 1.0500x over previous
//
#include <hip/hip_runtime.h>
#include <math.h>

// ---------------------------------------------------------------------------
// GraphConvolution: B=2, N=50000, D=64, E=800000, H=32
// R11: (a) bcols -> ushort (halves k_bucket's scattered-line writeback:
//      WRITE_SIZE 48MB ~= 1 dirty 64B line/edge; 2B payload halves the line
//      footprint). (b) k_row fuses both batches into one wave: edge list /
//      bcols / counts / gather addresses are batch-independent, so one wave
//      per row n does b=0 and b=1 together -> waves 100K->50K, shared
//      readlane/addr work, 16 gather chains in flight (was 8).
//      k_gemm / k_nd untouched (not visible in top-5; revisit next round).
// ---------------------------------------------------------------------------

#define CAP 64

__device__ __forceinline__ float elu_f(float x) {
    return x > 0.f ? x : __expf(x) - 1.f;
}
__device__ __forceinline__ unsigned short f2bf(float f) {   // RNE
    unsigned u = __float_as_uint(f);
    return (unsigned short)((u + 0x7fffu + ((u >> 16) & 1u)) >> 16);
}
__device__ __forceinline__ float bf2f(unsigned short h) {
    return __uint_as_float(((unsigned)h) << 16);
}

// --- tf(bf16) = x_infl @ W : block stages 64 rows in LDS; lane = out col ---
__global__ __launch_bounds__(256) void k_gemm(
    const float* __restrict__ x_infl, const float* __restrict__ Wg,
    unsigned short* __restrict__ tf16, int BN)
{
    __shared__ float4 xs4[1024];               // 64 rows x 16 float4 = 16 KB
    int tid = threadIdx.x;
    int lane = tid & 63;

    float wcol[64];                            // W[:, lane]
#pragma unroll
    for (int k = 0; k < 64; ++k) wcol[k] = Wg[k * 64 + lane];

    size_t gbase = (size_t)blockIdx.x * 1024;  // float4 units
    size_t gmax = (size_t)BN * 16 - 1;
    const float4* xg = (const float4*)x_infl;
#pragma unroll
    for (int q = 0; q < 4; ++q) {              // coalesced stage (clamped tail)
        size_t g = gbase + q * 256 + tid;
        xs4[q * 256 + tid] = xg[g > gmax ? gmax : g];
    }
    __syncthreads();

    int wrow = (tid >> 6) * 16;                // 16 rows per wave
    int r0 = blockIdx.x * 64;
    for (int rp = 0; rp < 8; ++rp) {           // 2 rows in flight (2 chains)
        int ra = wrow + rp * 2;
        float acca = 0.f, accb = 0.f;
#pragma unroll
        for (int k4 = 0; k4 < 16; ++k4) {
            float4 va = xs4[ra * 16 + k4];     // uniform addr -> broadcast
            float4 vb = xs4[ra * 16 + 16 + k4];
            acca = fmaf(va.x, wcol[4 * k4 + 0], acca);
            acca = fmaf(va.y, wcol[4 * k4 + 1], acca);
            acca = fmaf(va.z, wcol[4 * k4 + 2], acca);
            acca = fmaf(va.w, wcol[4 * k4 + 3], acca);
            accb = fmaf(vb.x, wcol[4 * k4 + 0], accb);
            accb = fmaf(vb.y, wcol[4 * k4 + 1], accb);
            accb = fmaf(vb.z, wcol[4 * k4 + 2], accb);
            accb = fmaf(vb.w, wcol[4 * k4 + 3], accb);
        }
        int g0 = r0 + ra, g1 = g0 + 1;
        if (g0 < BN) tf16[((size_t)g0 << 6) + lane] = f2bf(acca);
        if (g1 < BN) tf16[((size_t)g1 << 6) + lane] = f2bf(accb);
    }
}

// --- per-row dots via wB = W@beta (fp32-exact, reads x not tf) + gate MLP ---
__global__ __launch_bounds__(256) void k_nd(
    const float* __restrict__ x_infl, const float* __restrict__ Wg,
    const float* __restrict__ sbeta, const float* __restrict__ iatt,
    const float* __restrict__ x_state,
    const float* __restrict__ w1, const float* __restrict__ b1,
    const float* __restrict__ w2, const float* __restrict__ b2,
    float4* __restrict__ node4, float2* __restrict__ rpack, int BN)
{
    __shared__ float4 b4[64], wb4[64];
    int tid = threadIdx.x;
    if (tid < 64)
        b4[tid] = make_float4(sbeta[tid], sbeta[64 + tid],
                              iatt[tid], iatt[64 + tid]);
    __syncthreads();
    if (tid < 64) {                            // wB[k] = dot(W[k,:], beta_*)
        const float* wr = Wg + tid * 64;
        float asr = 0.f, asc = 0.f, aer = 0.f, aec = 0.f;
#pragma unroll
        for (int j = 0; j < 64; ++j) {
            float w = wr[j]; float4 bb = b4[j];
            asr = fmaf(w, bb.x, asr); asc = fmaf(w, bb.y, asc);
            aer = fmaf(w, bb.z, aer); aec = fmaf(w, bb.w, aec);
        }
        wb4[tid] = make_float4(asr, asc, aer, aec);
    }
    __syncthreads();

    int r = blockIdx.x * 256 + tid;
    int rr = (r < BN) ? r : BN - 1;
    const float4* xr = (const float4*)(x_infl + ((size_t)rr << 6));
    float sr = 0.f, sc = 0.f, er = 0.f, ec = 0.f;
#pragma unroll
    for (int k4 = 0; k4 < 16; ++k4) {
        float4 xv = xr[k4];
        float4 u0 = wb4[4 * k4 + 0], u1 = wb4[4 * k4 + 1];
        float4 u2 = wb4[4 * k4 + 2], u3 = wb4[4 * k4 + 3];
        sr = fmaf(xv.x, u0.x, sr); sc = fmaf(xv.x, u0.y, sc);
        er = fmaf(xv.x, u0.z, er); ec = fmaf(xv.x, u0.w, ec);
        sr = fmaf(xv.y, u1.x, sr); sc = fmaf(xv.y, u1.y, sc);
        er = fmaf(xv.y, u1.z, er); ec = fmaf(xv.y, u1.w, ec);
        sr = fmaf(xv.z, u2.x, sr); sc = fmaf(xv.z, u2.y, sc);
        er = fmaf(xv.z, u2.z, er); ec = fmaf(xv.z, u2.w, ec);
        sr = fmaf(xv.w, u3.x, sr); sc = fmaf(xv.w, u3.y, sc);
        er = fmaf(xv.w, u3.z, er); ec = fmaf(xv.w, u3.w, ec);
    }

    float xs = x_state[rr];
    float tacc = b2[0];
#pragma unroll
    for (int h = 0; h < 32; ++h)
        tacc = fmaf(elu_f(fmaf(xs, w1[h], b1[h])), w2[h], tacc);
    float gate = elu_f(tacc);

    if (r < BN) {
        node4[r] = make_float4(ec, sc, xs, gate);   // {e_c, s_c, xs, gate}
        rpack[r] = make_float2(er, sr);             // {e_r, s_r}
    }
}

// --- edge -> per-row bucket slot (one int atomicAdd; counts doubles as size)
// bcols is ushort: N=50000 < 65536, halves the scattered-line writeback.
__global__ __launch_bounds__(256) void k_bucket(const int2* __restrict__ Li,
                                                int* __restrict__ counts,
                                                unsigned short* __restrict__ bcols,
                                                int E) {
    int e = blockIdx.x * 256 + threadIdx.x;
    if (e < E) {
        int2 rc = Li[e];
        int p = atomicAdd(&counts[rc.x], 1);
        if (p < CAP) bcols[rc.x * CAP + p] = (unsigned short)rc.y;
    }
}

// --- heavy kernel: one wave per row n, BOTH batches fused (edge list is
//     batch-independent): shared bcols/counts/addr work, 16 gather chains ---
__global__ __launch_bounds__(256) void k_row(
    const int* __restrict__ counts, const unsigned short* __restrict__ bcols,
    const unsigned short* __restrict__ tf16, const float4* __restrict__ node4,
    const float2* __restrict__ rpack,
    const float* __restrict__ x_state, const float* __restrict__ self_act,
    const float* __restrict__ Xs,
    const float* __restrict__ sws_p, const float* __restrict__ swn_p,
    const float* __restrict__ iws_p, const float* __restrict__ iwn_p,
    float* __restrict__ out_state, float* __restrict__ out_infl, int N)
{
    int lane = threadIdx.x & 63;
    int n = blockIdx.x * 4 + __builtin_amdgcn_readfirstlane(threadIdx.x >> 6);

    int cnt = counts[n];                      // uniform -> s_load
    cnt = (cnt > CAP) ? CAP : cnt;

    float2 rp0 = rpack[n];
    float2 rp1 = rpack[N + n];
    const unsigned short* tfb0 = tf16;
    const unsigned short* tfb1 = tf16 + ((size_t)N << 6);

    float tsel0 = bf2f(tfb0[((size_t)n << 6) + lane]);   // issued early
    float tsel1 = bf2f(tfb1[((size_t)n << 6) + lane]);

    float lsum0 = 0.f, lsum1 = 0.f, sacc0 = 0.f, sacc1 = 0.f;
    float acc0[8], acc1[8];
#pragma unroll
    for (int j = 0; j < 8; ++j) { acc0[j] = 0.f; acc1[j] = 0.f; }

    if (cnt > 0) {
        bool act = lane < cnt;
        int c = bcols[n * CAP + (act ? lane : 0)];
        float4 ns0 = node4[c];                // {e_c, s_c, xs, gate} gathers
        float4 ns1 = node4[N + c];

        float lgs0 = rp0.y + ns0.y;
        lgs0 = (lgs0 > 0.f) ? lgs0 : 0.02f * lgs0;
        sacc0 = act ? lgs0 * ns0.z : 0.f;
        float lg0 = rp0.x + ns0.x;
        lg0 = (lg0 > 0.f) ? lg0 : 0.2f * lg0;
        float pp0 = act ? __expf(lg0) : 0.f;  // no-max softmax (|lg| tiny)
        lsum0 = pp0;
        float wgt0 = pp0 * ns0.w;             // fold gate

        float lgs1 = rp1.y + ns1.y;
        lgs1 = (lgs1 > 0.f) ? lgs1 : 0.02f * lgs1;
        sacc1 = act ? lgs1 * ns1.z : 0.f;
        float lg1 = rp1.x + ns1.x;
        lg1 = (lg1 > 0.f) ? lg1 : 0.2f * lg1;
        float pp1 = act ? __expf(lg1) : 0.f;
        lsum1 = pp1;
        float wgt1 = pp1 * ns1.w;

        // pack {bf16(wgt) | c16} per batch (inactive lanes: wgt == 0, col is
        // a real neighbor -> pad loads are cache-hot and harmless)
        unsigned pkA = ((unsigned)f2bf(wgt0) << 16) | (unsigned)c;
        unsigned pkB = ((unsigned)f2bf(wgt1) << 16) | (unsigned)c;

        int cnt8 = (cnt + 7) & ~7;
        for (int k = 0; k < cnt8; k += 8) {   // 16 independent chains in flight
#pragma unroll
            for (int j = 0; j < 8; ++j) {
                unsigned pA = (unsigned)__builtin_amdgcn_readlane((int)pkA, k + j);
                unsigned pB = (unsigned)__builtin_amdgcn_readlane((int)pkB, k + j);
                size_t off = ((size_t)(pA & 0xffffu) << 6) + lane;
                float w0 = __uint_as_float(pA & 0xffff0000u);
                float w1 = __uint_as_float(pB & 0xffff0000u);
                acc0[j] = fmaf(w0, bf2f(tfb0[off]), acc0[j]);
                acc1[j] = fmaf(w1, bf2f(tfb1[off]), acc1[j]);
            }
        }
    }
    float accA = (((acc0[0] + acc0[1]) + (acc0[2] + acc0[3])) +
                  ((acc0[4] + acc0[5]) + (acc0[6] + acc0[7])));
    float accB = (((acc1[0] + acc1[1]) + (acc1[2] + acc1[3])) +
                  ((acc1[4] + acc1[5]) + (acc1[6] + acc1[7])));

#pragma unroll
    for (int m = 1; m < 64; m <<= 1) {
        lsum0 += __shfl_xor(lsum0, m, 64);
        lsum1 += __shfl_xor(lsum1, m, 64);
        sacc0 += __shfl_xor(sacc0, m, 64);
        sacc1 += __shfl_xor(sacc1, m, 64);
    }

    float En0 = (cnt > 0) ? accA / lsum0 : 0.f;
    float En1 = (cnt > 0) ? accB / lsum1 : 0.f;

    float iws = iws_p[0], iwn = iwn_p[0];
    out_infl[((size_t)n << 6) + lane]       = elu_f(fmaf(iwn, En0, iws * tsel0));
    out_infl[((size_t)(N + n) << 6) + lane] = elu_f(fmaf(iwn, En1, iws * tsel1));

    if (lane == 0) {
        float sws = sws_p[0], swn = swn_p[0];
        float sa = self_act[n];

        float Sn0 = sacc0 + sa;
        float su0 = elu_f(fmaf(swn, Sn0, sws * x_state[n]));
        float X0 = Xs[n];
        out_state[n] = fmaf(su0, 1.f - X0, X0);

        float Sn1 = sacc1 + sa;
        float su1 = elu_f(fmaf(swn, Sn1, sws * x_state[N + n]));
        float X1 = Xs[N + n];
        out_state[N + n] = fmaf(su1, 1.f - X1, X1);
    }
}

extern "C" void kernel_launch(void* const* d_in, const int* in_sizes, int n_in,
                              void* d_out, int out_size, void* d_ws, size_t ws_size,
                              hipStream_t stream) {
    const float* x_state  = (const float*)d_in[0];
    const float* x_infl   = (const float*)d_in[1];
    const int*   L_ind    = (const int*)d_in[2];
    // d_in[3] = L_values: unused by the reference
    const float* self_act = (const float*)d_in[4];
    const float* Xs       = (const float*)d_in[5];
    const float* Wg       = (const float*)d_in[6];
    const float* sbeta    = (const float*)d_in[7];
    const float* sws      = (const float*)d_in[8];
    const float* swn      = (const float*)d_in[9];
    const float* w1       = (const float*)d_in[10];
    const float* b1       = (const float*)d_in[11];
    const float* w2       = (const float*)d_in[12];
    const float* b2       = (const float*)d_in[13];
    const float* iatt     = (const float*)d_in[14];
    const float* iws      = (const float*)d_in[15];
    const float* iwn      = (const float*)d_in[16];

    const int N  = in_sizes[4];        // 50000
    const int BN = in_sizes[0];        // 100000
    const int E  = in_sizes[2] / 2;    // 800000

    char* p = (char*)d_ws;
    auto alloc = [&](size_t bytes) {
        void* q = (void*)p;
        p += (bytes + 255) & ~(size_t)255;
        return q;
    };
    unsigned short* tf16  = (unsigned short*)alloc((size_t)BN * 64 * 2); // 12.8 MB
    float4*         node4 = (float4*)alloc((size_t)BN * 16);             //  1.6 MB
    float2*         rpack = (float2*)alloc((size_t)BN * 8);              //  0.8 MB
    int*            counts = (int*)  alloc((size_t)N * 4);               //  0.2 MB
    unsigned short* bcols = (unsigned short*)alloc((size_t)N * CAP * 2); //  6.4 MB

    hipMemsetAsync(counts, 0, (size_t)N * 4, stream);

    k_bucket<<<(E + 255) / 256, 256, 0, stream>>>((const int2*)L_ind,
                                                  counts, bcols, E);

    k_gemm<<<(BN + 63) / 64, 256, 0, stream>>>(x_infl, Wg, tf16, BN);

    k_nd<<<(BN + 255) / 256, 256, 0, stream>>>(x_infl, Wg, sbeta, iatt,
                                               x_state, w1, b1, w2, b2,
                                               node4, rpack, BN);

    k_row<<<N / 4, 256, 0, stream>>>(counts, bcols, tf16, node4, rpack,
                                     x_state, self_act, Xs,
                                     sws, swn, iws, iwn,
                                     (float*)d_out, (float*)d_out + BN, N);
}

// Round 2
// 191.006 us; speedup vs baseline: 1.2662x; 1.2060x over previous
//
#include <hip/hip_runtime.h>
#include <math.h>

// ---------------------------------------------------------------------------
// GraphConvolution: B=2, N=50000, D=64, E=800000, H=32
// R12: fuse k_bucket + k_gemm + k_nd into ONE kernel with interleaved block
//      roles (period 13 = 8 bucket : 4 gemm : 1 nd). The three are mutually
//      independent (only k_row consumes their outputs). k_bucket is
//      latency/line-writeback bound (VALUBusy 0.4%, 12% HBM) and leaves the
//      machine idle; co-scheduling hides it under gemm's VALU/LDS work.
//      R11 lesson: bcols payload width does NOT matter (~56B/edge dirty-line
//      writeback regardless) -> don't shrink payload, hide the kernel.
//      k_row unchanged from R11 (batch-fused, 16 gather chains).
// ---------------------------------------------------------------------------

#define CAP 64

__device__ __forceinline__ float elu_f(float x) {
    return x > 0.f ? x : __expf(x) - 1.f;
}
__device__ __forceinline__ unsigned short f2bf(float f) {   // RNE
    unsigned u = __float_as_uint(f);
    return (unsigned short)((u + 0x7fffu + ((u >> 16) & 1u)) >> 16);
}
__device__ __forceinline__ float bf2f(unsigned short h) {
    return __uint_as_float(((unsigned)h) << 16);
}

// --- fused: bucket (8/13) + gemm (4/13) + nd (1/13) ------------------------
__global__ __launch_bounds__(256) void k_fused(
    const int2* __restrict__ Li, int* __restrict__ counts,
    unsigned short* __restrict__ bcols, int E, int nb_b,
    const float* __restrict__ x_infl, const float* __restrict__ Wg,
    unsigned short* __restrict__ tf16, int BN, int nb_g,
    const float* __restrict__ sbeta, const float* __restrict__ iatt,
    const float* __restrict__ x_state,
    const float* __restrict__ w1, const float* __restrict__ b1,
    const float* __restrict__ w2, const float* __restrict__ b2,
    float4* __restrict__ node4, float2* __restrict__ rpack, int nb_n)
{
    __shared__ float4 xs4[1024];               // gemm: 64 rows x 16 float4;
                                               // nd aliases first 128 entries
    int tid = threadIdx.x;
    int bid = blockIdx.x;
    int per = bid / 13, q = bid % 13;

    if (q < 8) {
        // ---------------- bucket role ----------------
        int idx = per * 8 + q;
        if (idx >= nb_b) return;
        int e = idx * 256 + tid;
        if (e < E) {
            int2 rc = Li[e];
            int p = atomicAdd(&counts[rc.x], 1);
            if (p < CAP) bcols[rc.x * CAP + p] = (unsigned short)rc.y;
        }
        return;
    }

    if (q < 12) {
        // ---------------- gemm role: tf16 = bf16(x_infl @ W) ----------------
        int idx = per * 4 + (q - 8);
        if (idx >= nb_g) return;
        int lane = tid & 63;

        float wcol[64];                        // W[:, lane]
#pragma unroll
        for (int k = 0; k < 64; ++k) wcol[k] = Wg[k * 64 + lane];

        size_t gbase = (size_t)idx * 1024;     // float4 units
        size_t gmax = (size_t)BN * 16 - 1;
        const float4* xg = (const float4*)x_infl;
#pragma unroll
        for (int u = 0; u < 4; ++u) {          // coalesced stage (clamped tail)
            size_t g = gbase + u * 256 + tid;
            xs4[u * 256 + tid] = xg[g > gmax ? gmax : g];
        }
        __syncthreads();

        int wrow = (tid >> 6) * 16;            // 16 rows per wave
        int r0 = idx * 64;
        for (int rp = 0; rp < 8; ++rp) {       // 2 rows in flight
            int ra = wrow + rp * 2;
            float acca = 0.f, accb = 0.f;
#pragma unroll
            for (int k4 = 0; k4 < 16; ++k4) {
                float4 va = xs4[ra * 16 + k4]; // uniform addr -> broadcast
                float4 vb = xs4[ra * 16 + 16 + k4];
                acca = fmaf(va.x, wcol[4 * k4 + 0], acca);
                acca = fmaf(va.y, wcol[4 * k4 + 1], acca);
                acca = fmaf(va.z, wcol[4 * k4 + 2], acca);
                acca = fmaf(va.w, wcol[4 * k4 + 3], acca);
                accb = fmaf(vb.x, wcol[4 * k4 + 0], accb);
                accb = fmaf(vb.y, wcol[4 * k4 + 1], accb);
                accb = fmaf(vb.z, wcol[4 * k4 + 2], accb);
                accb = fmaf(vb.w, wcol[4 * k4 + 3], accb);
            }
            int g0 = r0 + ra, g1 = g0 + 1;
            if (g0 < BN) tf16[((size_t)g0 << 6) + lane] = f2bf(acca);
            if (g1 < BN) tf16[((size_t)g1 << 6) + lane] = f2bf(accb);
        }
        return;
    }

    {
        // ---------------- nd role: per-row dots + gate MLP ----------------
        int idx = per;
        if (idx >= nb_n) return;
        float4* b4  = xs4;                     // [64]
        float4* wb4 = xs4 + 64;                // [64]

        if (tid < 64)
            b4[tid] = make_float4(sbeta[tid], sbeta[64 + tid],
                                  iatt[tid], iatt[64 + tid]);
        __syncthreads();
        if (tid < 64) {                        // wB[k] = dot(W[k,:], beta_*)
            const float* wr = Wg + tid * 64;
            float asr = 0.f, asc = 0.f, aer = 0.f, aec = 0.f;
#pragma unroll
            for (int j = 0; j < 64; ++j) {
                float w = wr[j]; float4 bb = b4[j];
                asr = fmaf(w, bb.x, asr); asc = fmaf(w, bb.y, asc);
                aer = fmaf(w, bb.z, aer); aec = fmaf(w, bb.w, aec);
            }
            wb4[tid] = make_float4(asr, asc, aer, aec);
        }
        __syncthreads();

        int r = idx * 256 + tid;
        int rr = (r < BN) ? r : BN - 1;
        const float4* xr = (const float4*)(x_infl + ((size_t)rr << 6));
        float sr = 0.f, sc = 0.f, er = 0.f, ec = 0.f;
#pragma unroll
        for (int k4 = 0; k4 < 16; ++k4) {
            float4 xv = xr[k4];
            float4 u0 = wb4[4 * k4 + 0], u1 = wb4[4 * k4 + 1];
            float4 u2 = wb4[4 * k4 + 2], u3 = wb4[4 * k4 + 3];
            sr = fmaf(xv.x, u0.x, sr); sc = fmaf(xv.x, u0.y, sc);
            er = fmaf(xv.x, u0.z, er); ec = fmaf(xv.x, u0.w, ec);
            sr = fmaf(xv.y, u1.x, sr); sc = fmaf(xv.y, u1.y, sc);
            er = fmaf(xv.y, u1.z, er); ec = fmaf(xv.y, u1.w, ec);
            sr = fmaf(xv.z, u2.x, sr); sc = fmaf(xv.z, u2.y, sc);
            er = fmaf(xv.z, u2.z, er); ec = fmaf(xv.z, u2.w, ec);
            sr = fmaf(xv.w, u3.x, sr); sc = fmaf(xv.w, u3.y, sc);
            er = fmaf(xv.w, u3.z, er); ec = fmaf(xv.w, u3.w, ec);
        }

        float xs = x_state[rr];
        float tacc = b2[0];
#pragma unroll
        for (int h = 0; h < 32; ++h)
            tacc = fmaf(elu_f(fmaf(xs, w1[h], b1[h])), w2[h], tacc);
        float gate = elu_f(tacc);

        if (r < BN) {
            node4[r] = make_float4(ec, sc, xs, gate);  // {e_c, s_c, xs, gate}
            rpack[r] = make_float2(er, sr);            // {e_r, s_r}
        }
    }
}

// --- heavy kernel: one wave per row n, BOTH batches fused (edge list is
//     batch-independent): shared bcols/counts/addr work, 16 gather chains ---
__global__ __launch_bounds__(256) void k_row(
    const int* __restrict__ counts, const unsigned short* __restrict__ bcols,
    const unsigned short* __restrict__ tf16, const float4* __restrict__ node4,
    const float2* __restrict__ rpack,
    const float* __restrict__ x_state, const float* __restrict__ self_act,
    const float* __restrict__ Xs,
    const float* __restrict__ sws_p, const float* __restrict__ swn_p,
    const float* __restrict__ iws_p, const float* __restrict__ iwn_p,
    float* __restrict__ out_state, float* __restrict__ out_infl, int N)
{
    int lane = threadIdx.x & 63;
    int n = blockIdx.x * 4 + __builtin_amdgcn_readfirstlane(threadIdx.x >> 6);

    int cnt = counts[n];                      // uniform -> s_load
    cnt = (cnt > CAP) ? CAP : cnt;

    float2 rp0 = rpack[n];
    float2 rp1 = rpack[N + n];
    const unsigned short* tfb0 = tf16;
    const unsigned short* tfb1 = tf16 + ((size_t)N << 6);

    float tsel0 = bf2f(tfb0[((size_t)n << 6) + lane]);   // issued early
    float tsel1 = bf2f(tfb1[((size_t)n << 6) + lane]);

    float lsum0 = 0.f, lsum1 = 0.f, sacc0 = 0.f, sacc1 = 0.f;
    float acc0[8], acc1[8];
#pragma unroll
    for (int j = 0; j < 8; ++j) { acc0[j] = 0.f; acc1[j] = 0.f; }

    if (cnt > 0) {
        bool act = lane < cnt;
        int c = bcols[n * CAP + (act ? lane : 0)];
        float4 ns0 = node4[c];                // {e_c, s_c, xs, gate} gathers
        float4 ns1 = node4[N + c];

        float lgs0 = rp0.y + ns0.y;
        lgs0 = (lgs0 > 0.f) ? lgs0 : 0.02f * lgs0;
        sacc0 = act ? lgs0 * ns0.z : 0.f;
        float lg0 = rp0.x + ns0.x;
        lg0 = (lg0 > 0.f) ? lg0 : 0.2f * lg0;
        float pp0 = act ? __expf(lg0) : 0.f;  // no-max softmax (|lg| tiny)
        lsum0 = pp0;
        float wgt0 = pp0 * ns0.w;             // fold gate

        float lgs1 = rp1.y + ns1.y;
        lgs1 = (lgs1 > 0.f) ? lgs1 : 0.02f * lgs1;
        sacc1 = act ? lgs1 * ns1.z : 0.f;
        float lg1 = rp1.x + ns1.x;
        lg1 = (lg1 > 0.f) ? lg1 : 0.2f * lg1;
        float pp1 = act ? __expf(lg1) : 0.f;
        lsum1 = pp1;
        float wgt1 = pp1 * ns1.w;

        // pack {bf16(wgt) | c16} per batch (inactive lanes: wgt == 0, col is
        // a real neighbor -> pad loads are cache-hot and harmless)
        unsigned pkA = ((unsigned)f2bf(wgt0) << 16) | (unsigned)c;
        unsigned pkB = ((unsigned)f2bf(wgt1) << 16) | (unsigned)c;

        int cnt8 = (cnt + 7) & ~7;
        for (int k = 0; k < cnt8; k += 8) {   // 16 independent chains in flight
#pragma unroll
            for (int j = 0; j < 8; ++j) {
                unsigned pA = (unsigned)__builtin_amdgcn_readlane((int)pkA, k + j);
                unsigned pB = (unsigned)__builtin_amdgcn_readlane((int)pkB, k + j);
                size_t off = ((size_t)(pA & 0xffffu) << 6) + lane;
                float w0 = __uint_as_float(pA & 0xffff0000u);
                float w1 = __uint_as_float(pB & 0xffff0000u);
                acc0[j] = fmaf(w0, bf2f(tfb0[off]), acc0[j]);
                acc1[j] = fmaf(w1, bf2f(tfb1[off]), acc1[j]);
            }
        }
    }
    float accA = (((acc0[0] + acc0[1]) + (acc0[2] + acc0[3])) +
                  ((acc0[4] + acc0[5]) + (acc0[6] + acc0[7])));
    float accB = (((acc1[0] + acc1[1]) + (acc1[2] + acc1[3])) +
                  ((acc1[4] + acc1[5]) + (acc1[6] + acc1[7])));

#pragma unroll
    for (int m = 1; m < 64; m <<= 1) {
        lsum0 += __shfl_xor(lsum0, m, 64);
        lsum1 += __shfl_xor(lsum1, m, 64);
        sacc0 += __shfl_xor(sacc0, m, 64);
        sacc1 += __shfl_xor(sacc1, m, 64);
    }

    float En0 = (cnt > 0) ? accA / lsum0 : 0.f;
    float En1 = (cnt > 0) ? accB / lsum1 : 0.f;

    float iws = iws_p[0], iwn = iwn_p[0];
    out_infl[((size_t)n << 6) + lane]       = elu_f(fmaf(iwn, En0, iws * tsel0));
    out_infl[((size_t)(N + n) << 6) + lane] = elu_f(fmaf(iwn, En1, iws * tsel1));

    if (lane == 0) {
        float sws = sws_p[0], swn = swn_p[0];
        float sa = self_act[n];

        float Sn0 = sacc0 + sa;
        float su0 = elu_f(fmaf(swn, Sn0, sws * x_state[n]));
        float X0 = Xs[n];
        out_state[n] = fmaf(su0, 1.f - X0, X0);

        float Sn1 = sacc1 + sa;
        float su1 = elu_f(fmaf(swn, Sn1, sws * x_state[N + n]));
        float X1 = Xs[N + n];
        out_state[N + n] = fmaf(su1, 1.f - X1, X1);
    }
}

extern "C" void kernel_launch(void* const* d_in, const int* in_sizes, int n_in,
                              void* d_out, int out_size, void* d_ws, size_t ws_size,
                              hipStream_t stream) {
    const float* x_state  = (const float*)d_in[0];
    const float* x_infl   = (const float*)d_in[1];
    const int*   L_ind    = (const int*)d_in[2];
    // d_in[3] = L_values: unused by the reference
    const float* self_act = (const float*)d_in[4];
    const float* Xs       = (const float*)d_in[5];
    const float* Wg       = (const float*)d_in[6];
    const float* sbeta    = (const float*)d_in[7];
    const float* sws      = (const float*)d_in[8];
    const float* swn      = (const float*)d_in[9];
    const float* w1       = (const float*)d_in[10];
    const float* b1       = (const float*)d_in[11];
    const float* w2       = (const float*)d_in[12];
    const float* b2       = (const float*)d_in[13];
    const float* iatt     = (const float*)d_in[14];
    const float* iws      = (const float*)d_in[15];
    const float* iwn      = (const float*)d_in[16];

    const int N  = in_sizes[4];        // 50000
    const int BN = in_sizes[0];        // 100000
    const int E  = in_sizes[2] / 2;    // 800000

    char* p = (char*)d_ws;
    auto alloc = [&](size_t bytes) {
        void* q = (void*)p;
        p += (bytes + 255) & ~(size_t)255;
        return q;
    };
    unsigned short* tf16  = (unsigned short*)alloc((size_t)BN * 64 * 2); // 12.8 MB
    float4*         node4 = (float4*)alloc((size_t)BN * 16);             //  1.6 MB
    float2*         rpack = (float2*)alloc((size_t)BN * 8);              //  0.8 MB
    int*            counts = (int*)  alloc((size_t)N * 4);               //  0.2 MB
    unsigned short* bcols = (unsigned short*)alloc((size_t)N * CAP * 2); //  6.4 MB

    hipMemsetAsync(counts, 0, (size_t)N * 4, stream);

    const int nb_b = (E + 255) / 256;          // 3125 bucket blocks
    const int nb_g = (BN + 63) / 64;           // 1563 gemm blocks
    const int nb_n = (BN + 255) / 256;         //  391 nd blocks
    int P = (nb_b + 7) / 8;
    int Pg = (nb_g + 3) / 4; if (Pg > P) P = Pg;
    if (nb_n > P) P = nb_n;

    k_fused<<<13 * P, 256, 0, stream>>>((const int2*)L_ind, counts, bcols,
                                        E, nb_b,
                                        x_infl, Wg, tf16, BN, nb_g,
                                        sbeta, iatt, x_state,
                                        w1, b1, w2, b2, node4, rpack, nb_n);

    k_row<<<N / 4, 256, 0, stream>>>(counts, bcols, tf16, node4, rpack,
                                     x_state, self_act, Xs,
                                     sws, swn, iws, iwn,
                                     (float*)d_out, (float*)d_out + BN, N);
}